// Round 5
// baseline (568.661 us; speedup 1.0000x reference)
//
#include <hip/hip_runtime.h>
#include <hip/hip_bf16.h>

typedef __attribute__((ext_vector_type(8))) short bf16x8;
typedef __attribute__((ext_vector_type(4))) float f32x4;
typedef __attribute__((ext_vector_type(4))) unsigned int u32x4;

#define KCAT 9216            // 1024 base cols + 1024*8 spline cols
#define NTOK 8192
#define CH   1024
#define KHALF 4608           // split-K half
#define BK   64
#define NT   (KHALF / BK)    // 72 K-tiles per block

// ---------- helpers ----------
__device__ __forceinline__ unsigned short f2bf(float f) {
    union { float f; unsigned int u; } v; v.f = f;
    unsigned int r = v.u + 0x7fffu + ((v.u >> 16) & 1u);   // RNE
    return (unsigned short)(r >> 16);
}

__device__ __forceinline__ void load16_to_lds(const void* gp, void* lp) {
    __builtin_amdgcn_global_load_lds(
        (__attribute__((address_space(1))) void*)(void*)gp,
        (__attribute__((address_space(3))) void*)lp,
        16, 0, 0);
}

// Closed-form uniform cubic B-spline: the 8 basis values for x on knots
// t_j = -0.44 + 0.08j (j=0..11), packed as 8 bf16 into w[0..3].
// At x in [t_m, t_{m+1}) (m=0..10, else all-zero), active bases are
// j = m-3..m with values N0..N3 of u = (x-t_m)/h:
//   N0=(1-u)^3/6, N1=.5u^3-u^2+2/3, N3=u^3/6, N2=1-N0-N1-N3 (partition of 1).
__device__ __forceinline__ void bases8_cf(float x, unsigned int* w) {
    float p  = (x + 0.44f) * 12.5f;
    float mf = floorf(p);
    float u  = p - mf;
    int   m  = (int)mf;
    float v  = 1.0f - u;
    float u2 = u * u, u3 = u2 * u;
    float N0 = v * v * v * (1.0f / 6.0f);
    float N1 = 0.5f * u3 - u2 + (2.0f / 3.0f);
    float N3 = u3 * (1.0f / 6.0f);
    float N2 = 1.0f - N0 - N1 - N3;
    unsigned long long lo =
          (unsigned long long)f2bf(N0)
        | ((unsigned long long)f2bf(N1) << 16)
        | ((unsigned long long)f2bf(N2) << 32)
        | ((unsigned long long)f2bf(N3) << 48);
    lo = (m >= 0 && m <= 10) ? lo : 0ull;
    int sh  = (m - 3) * 16;          // window start in bits: -48..112
    int sh1 = sh - 64;
    unsigned long long d0 =
        (sh  >= 0) ? ((sh  < 64) ? (lo << sh)    : 0ull)
                   : ((-sh  < 64) ? (lo >> (-sh))  : 0ull);
    unsigned long long d1 =
        (sh1 >= 0) ? ((sh1 < 64) ? (lo << sh1)   : 0ull)
                   : ((-sh1 < 64) ? (lo >> (-sh1)) : 0ull);
    w[0] = (unsigned int)d0; w[1] = (unsigned int)(d0 >> 32);
    w[2] = (unsigned int)d1; w[3] = (unsigned int)(d1 >> 32);
}

// ---------- weight pack: [out,1024] f32 + [out,1024,8] f32 -> [out, 9216] bf16 ----------
__global__ __launch_bounds__(256) void conv_w(const float* __restrict__ BW,
                                              const float* __restrict__ SW,
                                              unsigned short* __restrict__ W) {
    int o = blockIdx.x;
    const float* bw = BW + (size_t)o * 1024;
    const float* sw = SW + (size_t)o * 8192;
    unsigned short* w = W + (size_t)o * KCAT;
    for (int c = threadIdx.x * 4; c < KCAT; c += 256 * 4) {
        const float* src = (c < 1024) ? (bw + c) : (sw + (c - 1024));
        float4 v = *(const float4*)src;
        unsigned short u[4] = { f2bf(v.x), f2bf(v.y), f2bf(v.z), f2bf(v.w) };
        *(unsigned long long*)(w + c) = *(unsigned long long*)u;
    }
}

// ---------- bf16 snapshot of the layer input (for base-col tiles) ----------
__global__ __launch_bounds__(256) void kan_x(const float* __restrict__ X,
                                             unsigned short* __restrict__ O, int total8) {
    for (int i = blockIdx.x * 256 + threadIdx.x; i < total8; i += gridDim.x * 256) {
        float4 a = ((const float4*)X)[i * 2];
        float4 b = ((const float4*)X)[i * 2 + 1];
        unsigned short o[8] = { f2bf(a.x), f2bf(a.y), f2bf(a.z), f2bf(a.w),
                                f2bf(b.x), f2bf(b.y), f2bf(b.z), f2bf(b.w) };
        *(bf16x8*)(O + (size_t)i * 8) = *(bf16x8*)o;
    }
}

__global__ __launch_bounds__(256) void kan_x_sum(const float* __restrict__ A,
                                                 const float* __restrict__ B,
                                                 unsigned short* __restrict__ O, int total8) {
    for (int i = blockIdx.x * 256 + threadIdx.x; i < total8; i += gridDim.x * 256) {
        float4 a0 = ((const float4*)A)[i * 2],     b0 = ((const float4*)B)[i * 2];
        float4 a1 = ((const float4*)A)[i * 2 + 1], b1 = ((const float4*)B)[i * 2 + 1];
        unsigned short o[8] = { f2bf(a0.x + b0.x), f2bf(a0.y + b0.y), f2bf(a0.z + b0.z), f2bf(a0.w + b0.w),
                                f2bf(a1.x + b1.x), f2bf(a1.y + b1.y), f2bf(a1.z + b1.z), f2bf(a1.w + b1.w) };
        *(bf16x8*)(O + (size_t)i * 8) = *(bf16x8*)o;
    }
}

// ---------- final split-K reduction ----------
__global__ __launch_bounds__(256) void add_out(const float* __restrict__ C0,
                                               const float* __restrict__ C1,
                                               float* __restrict__ out, int total4) {
    for (int i = blockIdx.x * 256 + threadIdx.x; i < total4; i += gridDim.x * 256) {
        float4 a = ((const float4*)C0)[i];
        float4 b = ((const float4*)C1)[i];
        float4 r = { a.x + b.x, a.y + b.y, a.z + b.z, a.w + b.w };
        ((float4*)out)[i] = r;
    }
}

// ---------- fused 256x256 split-K GEMM with in-staging basis expansion ----------
// A-tile sources: base tiles (kz==0, t<16) <- Xb16 via global_load_lds;
// spline tiles <- 8 x-values/row computed to bases in-register, ds_write (swizzled).
// B from packed W. Read path identical to round-4 (measured 0 bank conflicts).
template<bool SUM>
__global__ __launch_bounds__(512, 2) void gemm_fused(const float* __restrict__ XA,
                                                     const float* __restrict__ XB,
                                                     const unsigned short* __restrict__ Xb16,
                                                     const unsigned short* __restrict__ W,
                                                     float* __restrict__ C0,
                                                     float* __restrict__ C1) {
    __shared__ __align__(16) unsigned short As[2 * 256 * 64];
    __shared__ __align__(16) unsigned short Bs[2 * 256 * 64];
    const int tid  = threadIdx.x;
    const int lane = tid & 63;
    const int wid  = tid >> 6;
    const int wr = wid >> 2, wc = wid & 3;       // wave grid 2(M) x 4(N)
    const int ln = lane & 15, q = lane >> 4;

    const int bid = blockIdx.x;                  // 0..255
    const int xcd = bid & 7, ii = bid >> 3;
    const int kz = xcd & 1, chm = xcd >> 1;
    const int bm = chm * 8 + (ii & 7);           // 0..31
    const int bn = ii >> 3;                      // 0..3

    const int sr  = tid >> 1;                    // staging row 0..255
    const int sf0 = (tid & 1) * 4;               // staging feature offset 0/4

    const unsigned short* Bb = W    + (size_t)(bn * 256) * KCAT + (size_t)kz * KHALF;
    const unsigned short* Xb = Xb16 + (size_t)(bm * 256) * CH;
    const float* xa = XA + (size_t)(bm * 256 + sr) * CH + sf0;
    const float* xb = XB + (size_t)(bm * 256 + sr) * CH + sf0;
    float* C = (kz == 0) ? C0 : C1;

    f32x4 acc[8][4] = {};

    auto stage_B = [&](int t, int d, int part) {
        int chunk = part * 512 + tid;
        int r = chunk >> 3;
        int slot = (chunk & 7) ^ (r & 7);        // inverse swizzle on SOURCE
        size_t goff = (size_t)r * (KCAT * 2) + (size_t)t * (BK * 2) + slot * 16;
        load16_to_lds((const char*)Bb + goff, (char*)Bs + (size_t)d * 32768 + chunk * 16);
    };
    auto stage_Ab = [&](int t, int d, int part) {   // base tile from Xb16
        int chunk = part * 512 + tid;
        int r = chunk >> 3;
        int slot = (chunk & 7) ^ (r & 7);
        size_t goff = (size_t)r * (CH * 2) + (size_t)t * (BK * 2) + slot * 16;
        load16_to_lds((const char*)Xb + goff, (char*)As + (size_t)d * 32768 + chunk * 16);
    };
    auto load_x = [&](int t) -> float4 {            // 4 x-values for next spline tile
        int io = (kz == 0) ? (t * 8 - 128) : (448 + t * 8);
        float4 xv = *(const float4*)(xa + io);
        if (SUM) {
            float4 y = *(const float4*)(xb + io);
            xv.x += y.x; xv.y += y.y; xv.z += y.z; xv.w += y.w;
        }
        return xv;
    };
    auto spline_cw = [&](float4 xv, int d) {        // compute bases, swizzled ds_write
        char* basep = (char*)As + (size_t)d * 32768 + sr * 128;
#pragma unroll
        for (int j = 0; j < 4; ++j) {
            float xj = (j == 0) ? xv.x : (j == 1) ? xv.y : (j == 2) ? xv.z : xv.w;
            unsigned int wv[4];
            bases8_cf(xj, wv);
            *(u32x4*)(basep + (((sf0 + j) ^ (sr & 7)) * 16)) = (u32x4){wv[0], wv[1], wv[2], wv[3]};
        }
    };

    // prologue: tile 0 -> buf 0  (kz==0: base tile; kz==1: spline tile i0=448)
    if (kz == 0) {
#pragma unroll
        for (int part = 0; part < 4; ++part) { stage_Ab(0, 0, part); stage_B(0, 0, part); }
    } else {
        float4 xv = load_x(0);
        spline_cw(xv, 0);
#pragma unroll
        for (int part = 0; part < 4; ++part) stage_B(0, 0, part);
    }
    asm volatile("s_waitcnt vmcnt(0) lgkmcnt(0)" ::: "memory");
    __builtin_amdgcn_s_barrier();

    for (int t = 0; t < NT; ++t) {
        const int c = t & 1;
        const char* Ap = (const char*)As + c * 32768;
        const char* Bp = (const char*)Bs + c * 32768;
        const bool pref = (t + 1 < NT);
        const bool nspl = pref && (kz == 1 || (t + 1) >= 16);   // next tile is spline
        float4 xva;
        bf16x8 bfr[4][2];
#pragma unroll
        for (int p = 0; p < 4; ++p) {
            bf16x8 afr[2][2];
#pragma unroll
            for (int m2 = 0; m2 < 2; ++m2)
#pragma unroll
                for (int kh = 0; kh < 2; ++kh) {
                    int row = wr * 128 + (p * 2 + m2) * 16 + ln;
                    int byte = row * 128 + ((kh * 64 + q * 16) ^ ((row & 7) * 16));
                    afr[m2][kh] = *(const bf16x8*)(Ap + byte);
                }
            if (p == 0) {
#pragma unroll
                for (int nf = 0; nf < 4; ++nf)
#pragma unroll
                    for (int kh = 0; kh < 2; ++kh) {
                        int row = wc * 64 + nf * 16 + ln;
                        int byte = row * 128 + ((kh * 64 + q * 16) ^ ((row & 7) * 16));
                        bfr[nf][kh] = *(const bf16x8*)(Bp + byte);
                    }
            }
            // staging slots for tile t+1 -> buf c^1
            if (pref) {
                if (nspl) {
                    if (p == 0) {
                        xva = load_x(t + 1);                    // reg load; compiler waits at use
                        stage_B(t + 1, c ^ 1, 0); stage_B(t + 1, c ^ 1, 1);
                    } else if (p == 1) {
                        stage_B(t + 1, c ^ 1, 2); stage_B(t + 1, c ^ 1, 3);
                    } else if (p == 2) {
                        spline_cw(xva, c ^ 1);                  // VALU + ds_write, ~2 phases after load
                    }
                } else {
                    if (p == 0) { stage_Ab(t + 1, c ^ 1, 0); stage_Ab(t + 1, c ^ 1, 1);
                                  stage_B (t + 1, c ^ 1, 0); stage_B (t + 1, c ^ 1, 1); }
                    else if (p == 1) { stage_Ab(t + 1, c ^ 1, 2); stage_Ab(t + 1, c ^ 1, 3);
                                       stage_B (t + 1, c ^ 1, 2); stage_B (t + 1, c ^ 1, 3); }
                }
            }
            __builtin_amdgcn_s_barrier();
            asm volatile("s_waitcnt lgkmcnt(0)" ::: "memory");  // phase reads + my ds_writes
            __builtin_amdgcn_sched_barrier(0);
            __builtin_amdgcn_s_setprio(1);
#pragma unroll
            for (int m2 = 0; m2 < 2; ++m2)
#pragma unroll
                for (int nf = 0; nf < 4; ++nf)
#pragma unroll
                    for (int kh = 0; kh < 2; ++kh)
                        acc[p * 2 + m2][nf] = __builtin_amdgcn_mfma_f32_16x16x32_bf16(
                            afr[m2][kh], bfr[nf][kh], acc[p * 2 + m2][nf], 0, 0, 0);
            __builtin_amdgcn_s_setprio(0);
            if (p == 3)  // publish next buffer: oldest B-load has 3 phases of cover
                asm volatile("s_waitcnt vmcnt(0)" ::: "memory");
            __builtin_amdgcn_s_barrier();
        }
    }

    // epilogue: C/D layout col=lane&15, row=(lane>>4)*4+reg [m89-verified]
#pragma unroll
    for (int mf = 0; mf < 8; ++mf)
#pragma unroll
        for (int nf = 0; nf < 4; ++nf)
#pragma unroll
            for (int r = 0; r < 4; ++r) {
                int row = bm * 256 + wr * 128 + mf * 16 + q * 4 + r;
                int col = bn * 256 + wc * 64 + nf * 16 + ln;
                C[(size_t)row * CH + col] = acc[mf][nf][r];
            }
}

// ---------- launch ----------
extern "C" void kernel_launch(void* const* d_in, const int* in_sizes, int n_in,
                              void* d_out, int out_size, void* d_ws, size_t ws_size,
                              hipStream_t stream) {
    const float* x   = (const float*)d_in[0];
    const float* bw1 = (const float*)d_in[1];
    const float* sw1 = (const float*)d_in[2];
    const float* bw2 = (const float*)d_in[3];
    const float* sw2 = (const float*)d_in[4];
    float* out = (float*)d_out;

    char* ws = (char*)d_ws;
    unsigned short* Wbuf = (unsigned short*)ws;                  //  18,874,368 B
    float* C0 = (float*)(ws + 18874368);                         //  33,554,432 B
    float* C1 = (float*)(ws + 52428800);
    float* D0 = (float*)(ws + 85983232);
    float* D1 = (float*)(ws + 119537664);
    unsigned short* Xb  = (unsigned short*)(ws + 153092096);     //  16,777,216 B
    unsigned short* X1b = (unsigned short*)(ws + 169869312);     //  16,777,216 B

    dim3 blk(256);

    // layer 1
    conv_w           <<<dim3(1024), blk, 0, stream>>>(bw1, sw1, Wbuf);
    kan_x            <<<dim3(2048), blk, 0, stream>>>(x, Xb, NTOK * CH / 8);
    gemm_fused<false><<<dim3(256), dim3(512), 0, stream>>>(x, x, Xb, Wbuf, C0, C1);

    // layer 2
    conv_w           <<<dim3(1024), blk, 0, stream>>>(bw2, sw2, Wbuf);
    kan_x_sum        <<<dim3(2048), blk, 0, stream>>>(C0, C1, X1b, NTOK * CH / 8);
    gemm_fused<true> <<<dim3(256), dim3(512), 0, stream>>>(C0, C1, X1b, Wbuf, D0, D1);
    add_out          <<<dim3(1024), blk, 0, stream>>>(D0, D1, out, NTOK * CH / 4);
}

// Round 6
// 544.831 us; speedup vs baseline: 1.0437x; 1.0437x over previous
//
#include <hip/hip_runtime.h>
#include <hip/hip_bf16.h>

typedef __attribute__((ext_vector_type(8))) short bf16x8;
typedef __attribute__((ext_vector_type(4))) float f32x4;
typedef __attribute__((ext_vector_type(4))) unsigned int u32x4;

#define KCAT 9216            // 1024 base cols + 1024*8 spline cols
#define NTOK 8192
#define CH   1024
#define KHALF 4608           // split-K half (per kz)
#define BK   64
#define NT   (KHALF / BK)    // 72 K-tiles per block
#define NH   (2 * NT)        // 144 half-tiles (K=32 each)

// ---------- helpers ----------
__device__ __forceinline__ unsigned short f2bf(float f) {
    union { float f; unsigned int u; } v; v.f = f;
    unsigned int r = v.u + 0x7fffu + ((v.u >> 16) & 1u);   // RNE
    return (unsigned short)(r >> 16);
}

__device__ __forceinline__ void load16_to_lds(const void* gp, void* lp) {
    __builtin_amdgcn_global_load_lds(
        (__attribute__((address_space(1))) void*)(void*)gp,
        (__attribute__((address_space(3))) void*)lp,
        16, 0, 0);
}

// Closed-form uniform cubic B-spline (HW-validated round 5): 8 bf16 bases
// packed into w[0..3] for knots t_j = -0.44 + 0.08j.
__device__ __forceinline__ void bases8_cf(float x, unsigned int* w) {
    float p  = (x + 0.44f) * 12.5f;
    float mf = floorf(p);
    float u  = p - mf;
    int   m  = (int)mf;
    float v  = 1.0f - u;
    float u2 = u * u, u3 = u2 * u;
    float N0 = v * v * v * (1.0f / 6.0f);
    float N1 = 0.5f * u3 - u2 + (2.0f / 3.0f);
    float N3 = u3 * (1.0f / 6.0f);
    float N2 = 1.0f - N0 - N1 - N3;
    unsigned long long lo =
          (unsigned long long)f2bf(N0)
        | ((unsigned long long)f2bf(N1) << 16)
        | ((unsigned long long)f2bf(N2) << 32)
        | ((unsigned long long)f2bf(N3) << 48);
    lo = (m >= 0 && m <= 10) ? lo : 0ull;
    int sh  = (m - 3) * 16;
    int sh1 = sh - 64;
    unsigned long long d0 =
        (sh  >= 0) ? ((sh  < 64) ? (lo << sh)    : 0ull)
                   : ((-sh  < 64) ? (lo >> (-sh))  : 0ull);
    unsigned long long d1 =
        (sh1 >= 0) ? ((sh1 < 64) ? (lo << sh1)   : 0ull)
                   : ((-sh1 < 64) ? (lo >> (-sh1)) : 0ull);
    w[0] = (unsigned int)d0; w[1] = (unsigned int)(d0 >> 32);
    w[2] = (unsigned int)d1; w[3] = (unsigned int)(d1 >> 32);
}

// conv_w body: pack one output row o of [base|spline] weights to bf16
__device__ __forceinline__ void conv_w_body(const float* __restrict__ BW,
                                            const float* __restrict__ SW,
                                            unsigned short* __restrict__ W, int o) {
    const float* bw = BW + (size_t)o * 1024;
    const float* sw = SW + (size_t)o * 8192;
    unsigned short* w = W + (size_t)o * KCAT;
    for (int c = threadIdx.x * 4; c < KCAT; c += 256 * 4) {
        const float* src = (c < 1024) ? (bw + c) : (sw + (c - 1024));
        float4 v = *(const float4*)src;
        unsigned short u[4] = { f2bf(v.x), f2bf(v.y), f2bf(v.z), f2bf(v.w) };
        *(unsigned long long*)(w + c) = *(unsigned long long*)u;
    }
}

// basis body: A[n][i]=bf16(x); A[n][1024+8i..+8]=bases
__device__ __forceinline__ void basis_body(float x, unsigned short* __restrict__ A, int idx) {
    int n = idx >> 10, i = idx & 1023;
    size_t rowbase = (size_t)n * KCAT;
    A[rowbase + i] = f2bf(x);
    unsigned int w[4];
    bases8_cf(x, w);
    *(u32x4*)(A + rowbase + 1024 + (size_t)i * 8) = (u32x4){w[0], w[1], w[2], w[3]};
}

// ---------- prep: blocks 0-1023 pack W1; 1024-3071 expand basis(x) ----------
__global__ __launch_bounds__(256) void prep1(const float* __restrict__ BW1,
                                             const float* __restrict__ SW1,
                                             unsigned short* __restrict__ W,
                                             const float* __restrict__ X,
                                             unsigned short* __restrict__ A) {
    int b = blockIdx.x;
    if (b < 1024) { conv_w_body(BW1, SW1, W, b); return; }
    int bb = b - 1024;
    for (int idx = bb * 256 + threadIdx.x; idx < NTOK * CH; idx += 2048 * 256)
        basis_body(X[idx], A, idx);
}

// ---------- mid: blocks 0-1023 pack W2; 1024-3071 expand basis(C0+C1) ----------
__global__ __launch_bounds__(256) void mid2(const float* __restrict__ BW2,
                                            const float* __restrict__ SW2,
                                            unsigned short* __restrict__ W,
                                            const float* __restrict__ C0,
                                            const float* __restrict__ C1,
                                            unsigned short* __restrict__ A) {
    int b = blockIdx.x;
    if (b < 1024) { conv_w_body(BW2, SW2, W, b); return; }
    int bb = b - 1024;
    for (int idx = bb * 256 + threadIdx.x; idx < NTOK * CH; idx += 2048 * 256)
        basis_body(C0[idx] + C1[idx], A, idx);
}

// ---------- final split-K reduction ----------
__global__ __launch_bounds__(256) void add_out(const float* __restrict__ C0,
                                               const float* __restrict__ C1,
                                               float* __restrict__ out, int total4) {
    for (int i = blockIdx.x * 256 + threadIdx.x; i < total4; i += gridDim.x * 256) {
        float4 a = ((const float4*)C0)[i];
        float4 b = ((const float4*)C1)[i];
        float4 r = { a.x + b.x, a.y + b.y, a.z + b.z, a.w + b.w };
        ((float4*)out)[i] = r;
    }
}

// ---------- 256x256 split-K GEMM, counted-vmcnt half-K pipeline (T3+T4) ----------
// K split into K=32 halves H_j (j = 2t+kh). Ring of 4 half-buffers (slot j&3,
// 16KB A + 16KB B each; 128KiB total). While computing H_j (2 phases of 16
// MFMA), issue H_{j+2}'s 4 loads. Half-boundary waits vmcnt(4): H_{j+1}
// landed, H_{j+2} in flight -> never drains in steady state.
// Swizzle: 64B rows, slot = q ^ ((row>>1)&3); inverse applied on global source.
__global__ __launch_bounds__(512, 2) void gemm256_splitk(const unsigned short* __restrict__ A,
                                                         const unsigned short* __restrict__ B,
                                                         float* __restrict__ C0,
                                                         float* __restrict__ C1) {
    __shared__ __align__(16) unsigned short As[4 * 256 * 32];
    __shared__ __align__(16) unsigned short Bs[4 * 256 * 32];
    const int tid  = threadIdx.x;
    const int lane = tid & 63;
    const int wid  = tid >> 6;
    const int wr = wid >> 2, wc = wid & 3;       // wave grid 2(M) x 4(N)
    const int ln = lane & 15, q = lane >> 4;

    const int bid = blockIdx.x;                  // 0..255, XCD-partitioned
    const int xcd = bid & 7, ii = bid >> 3;
    const int kz = xcd & 1, chm = xcd >> 1;
    const int bm = chm * 8 + (ii & 7);           // 0..31
    const int bn = ii >> 3;                      // 0..3

    const unsigned short* Ab = A + (size_t)(bm * 256) * KCAT + (size_t)kz * KHALF;
    const unsigned short* Bb = B + (size_t)(bn * 256) * KCAT + (size_t)kz * KHALF;
    float* C = (kz == 0) ? C0 : C1;

    f32x4 acc[8][4] = {};

    // stage 2 loads (one 16KB half-matrix) for half-tile (ts, ks) -> slot ds
    auto stageA2 = [&](int ts, int ks, int ds) {
#pragma unroll
        for (int part = 0; part < 2; ++part) {
            int c = part * 512 + tid;            // 0..1023
            int r = c >> 2;                      // row 0..255
            int gslot = (c & 3) ^ ((r >> 1) & 3);
            size_t goff = (size_t)r * (KCAT * 2) + (size_t)ts * 128 + ks * 64 + gslot * 16;
            load16_to_lds((const char*)Ab + goff, (char*)As + (size_t)ds * 16384 + c * 16);
        }
    };
    auto stageB2 = [&](int ts, int ks, int ds) {
#pragma unroll
        for (int part = 0; part < 2; ++part) {
            int c = part * 512 + tid;
            int r = c >> 2;
            int gslot = (c & 3) ^ ((r >> 1) & 3);
            size_t goff = (size_t)r * (KCAT * 2) + (size_t)ts * 128 + ks * 64 + gslot * 16;
            load16_to_lds((const char*)Bb + goff, (char*)Bs + (size_t)ds * 16384 + c * 16);
        }
    };

    // prologue: H0 -> slot0, H1 -> slot1 (8 loads); wait H0 (vmcnt(4))
    stageA2(0, 0, 0); stageB2(0, 0, 0);
    stageA2(0, 1, 1); stageB2(0, 1, 1);
    asm volatile("s_waitcnt vmcnt(4)" ::: "memory");
    __builtin_amdgcn_s_barrier();

    for (int t = 0; t < NT; ++t) {
#pragma unroll
        for (int kh = 0; kh < 2; ++kh) {
            const int j  = 2 * t + kh;
            const int sl = j & 3;
            const char* Ah = (const char*)As + sl * 16384;
            const char* Bh = (const char*)Bs + sl * 16384;
            const int jn = j + 2;
            const bool pf = jn < NH;
            const int ts = jn >> 1, ks = jn & 1, ds = jn & 3;
            bf16x8 bfr[4];
#pragma unroll
            for (int ph = 0; ph < 2; ++ph) {
                bf16x8 afr[4];
#pragma unroll
                for (int m = 0; m < 4; ++m) {
                    int row = wr * 128 + (ph * 4 + m) * 16 + ln;
                    afr[m] = *(const bf16x8*)(Ah + row * 64 + ((q ^ ((row >> 1) & 3)) * 16));
                }
                if (ph == 0) {
#pragma unroll
                    for (int nf = 0; nf < 4; ++nf) {
                        int row = wc * 64 + nf * 16 + ln;
                        bfr[nf] = *(const bf16x8*)(Bh + row * 64 + ((q ^ ((row >> 1) & 3)) * 16));
                    }
                }
                if (pf) { if (ph == 0) stageA2(ts, ks, ds); else stageB2(ts, ks, ds); }
                __builtin_amdgcn_s_barrier();
                asm volatile("s_waitcnt lgkmcnt(0)" ::: "memory");
                __builtin_amdgcn_sched_barrier(0);
                __builtin_amdgcn_s_setprio(1);
#pragma unroll
                for (int m = 0; m < 4; ++m)
#pragma unroll
                    for (int nf = 0; nf < 4; ++nf)
                        acc[ph * 4 + m][nf] = __builtin_amdgcn_mfma_f32_16x16x32_bf16(
                            afr[m], bfr[nf], acc[ph * 4 + m][nf], 0, 0, 0);
                __builtin_amdgcn_s_setprio(0);
                if (ph == 1) {
                    if (pf)               asm volatile("s_waitcnt vmcnt(4)" ::: "memory");
                    else if (j + 1 < NH)  asm volatile("s_waitcnt vmcnt(0)" ::: "memory");
                }
                __builtin_amdgcn_s_barrier();
            }
        }
    }

    // epilogue: C/D layout col=lane&15, row=(lane>>4)*4+reg [m89-verified]
#pragma unroll
    for (int mf = 0; mf < 8; ++mf)
#pragma unroll
        for (int nf = 0; nf < 4; ++nf)
#pragma unroll
            for (int r = 0; r < 4; ++r) {
                int row = bm * 256 + wr * 128 + mf * 16 + q * 4 + r;
                int col = bn * 256 + wc * 64 + nf * 16 + ln;
                C[(size_t)row * CH + col] = acc[mf][nf][r];
            }
}

// ---------- launch ----------
extern "C" void kernel_launch(void* const* d_in, const int* in_sizes, int n_in,
                              void* d_out, int out_size, void* d_ws, size_t ws_size,
                              hipStream_t stream) {
    const float* x   = (const float*)d_in[0];
    const float* bw1 = (const float*)d_in[1];
    const float* sw1 = (const float*)d_in[2];
    const float* bw2 = (const float*)d_in[3];
    const float* sw2 = (const float*)d_in[4];
    float* out = (float*)d_out;

    char* ws = (char*)d_ws;
    unsigned short* Abuf = (unsigned short*)ws;                    // 150,994,944 B
    unsigned short* Wbuf = (unsigned short*)(ws + 150994944);      //  18,874,368 B
    float* C0 = (float*)(ws + 150994944 + 18874368);               //  33,554,432 B
    float* C1 = (float*)(ws + 150994944 + 18874368 + 33554432);    //  33,554,432 B

    // layer 1
    prep1         <<<dim3(3072), dim3(256), 0, stream>>>(bw1, sw1, Wbuf, x, Abuf);
    gemm256_splitk<<<dim3(256), dim3(512), 0, stream>>>(Abuf, Wbuf, C0, C1);

    // layer 2 (W2 pack + split-K reduce + basis, one kernel)
    mid2          <<<dim3(3072), dim3(256), 0, stream>>>(bw2, sw2, Wbuf, C0, C1, Abuf);
    gemm256_splitk<<<dim3(256), dim3(512), 0, stream>>>(Abuf, Wbuf, C0, C1);
    add_out       <<<dim3(1024), dim3(256), 0, stream>>>(C0, C1, out, NTOK * CH / 4);
}